// Round 1
// baseline (316.494 us; speedup 1.0000x reference)
//
#include <hip/hip_runtime.h>

// LoRA embedding: out = E[idx] + (E[idx] @ A) @ B + bias
//   idx: [T] int32, E: [50257,1024] f32, A: [1024,8] f32, B: [8,1024] f32,
//   bias: [1024] f32, out: [T,1024] f32.
// One wave (64 lanes) per token. A (transposed) + B staged in 64 KB LDS per
// block so per-wave operand reads hit LDS instead of hammering L1/L2.

constexpr int F = 1024;
constexpr int R = 8;
constexpr int TOKS_PER_BLOCK = 16;           // 16 waves per block
constexpr int TPB = TOKS_PER_BLOCK * 64;     // 1024 threads

__global__ __launch_bounds__(TPB)
void lora_embedding_kernel(const int* __restrict__ idx,
                           const float* __restrict__ emb,
                           const float* __restrict__ A,
                           const float* __restrict__ Bm,
                           const float* __restrict__ bias,
                           float* __restrict__ out,
                           int ntok)
{
    // sAT[r][f] = A[f][r]  (transposed so per-r reads are contiguous in f)
    // sB [r][f] = B[r][f]  (already row-major [8][1024])
    __shared__ float sAT[R][F];   // 32 KB
    __shared__ float sB[R][F];    // 32 KB  -> 64 KB total

    const int t = threadIdx.x;

    // --- cooperative staging: A,B are each 8192 floats = 2048 float4 ---
    {
        const float4* A4 = reinterpret_cast<const float4*>(A);
        const float4* B4 = reinterpret_cast<const float4*>(Bm);
        float4* sB4 = reinterpret_cast<float4*>(&sB[0][0]);
        #pragma unroll
        for (int i = 0; i < (F * R / 4) / TPB; ++i) {   // 2 iterations
            const int n4 = t + i * TPB;                 // float4 index
            // flat elem n = n4*4 = f*8 + r  ->  f = n4>>1, r0 = (n4&1)*4
            const float4 a = A4[n4];
            const int f0 = n4 >> 1;
            const int r0 = (n4 & 1) * 4;
            sAT[r0 + 0][f0] = a.x;   // 2-way bank alias at worst (free)
            sAT[r0 + 1][f0] = a.y;
            sAT[r0 + 2][f0] = a.z;
            sAT[r0 + 3][f0] = a.w;
            sB4[n4] = B4[n4];        // same layout, straight copy
        }
    }
    __syncthreads();

    const int wave = t >> 6;
    const int lane = t & 63;
    const int tok = blockIdx.x * TOKS_PER_BLOCK + wave;
    if (tok >= ntok) return;

    const int row = idx[tok];
    const float4* src = reinterpret_cast<const float4*>(emb + (size_t)row * F);

    // Load the whole 4 KB row: 4 x float4 per lane, each instruction is a
    // contiguous 1 KB wave transaction (lane stride 16 B).
    float4 v[4];
    #pragma unroll
    for (int k = 0; k < 4; ++k) v[k] = src[lane + 64 * k];

    // low[r] = dot(base, A[:,r]) : per-lane partials, then 6-stage butterfly
    float p[R];
    #pragma unroll
    for (int r = 0; r < R; ++r) {
        float s = 0.f;
        #pragma unroll
        for (int k = 0; k < 4; ++k) {
            const float4 a =
                *reinterpret_cast<const float4*>(&sAT[r][4 * (lane + 64 * k)]);
            s += v[k].x * a.x + v[k].y * a.y + v[k].z * a.z + v[k].w * a.w;
        }
        #pragma unroll
        for (int off = 32; off >= 1; off >>= 1)
            s += __shfl_xor(s, off, 64);
        p[r] = s;   // every lane holds the full dot product
    }

    // out[f] = base[f] + bias[f] + sum_r p[r] * B[r][f]
    float4* dst = reinterpret_cast<float4*>(out + (size_t)tok * F);
    const float4* bias4 = reinterpret_cast<const float4*>(bias);
    #pragma unroll
    for (int k = 0; k < 4; ++k) {
        const int q = lane + 64 * k;           // float4 index within the row
        float4 o = v[k];
        const float4 bi = bias4[q];            // 4 KB, L1-hot
        o.x += bi.x; o.y += bi.y; o.z += bi.z; o.w += bi.w;
        #pragma unroll
        for (int r = 0; r < R; ++r) {
            const float4 b =
                *reinterpret_cast<const float4*>(&sB[r][4 * q]);
            o.x += p[r] * b.x;
            o.y += p[r] * b.y;
            o.z += p[r] * b.z;
            o.w += p[r] * b.w;
        }
        dst[q] = o;                            // contiguous 1 KB wave store
    }
}

extern "C" void kernel_launch(void* const* d_in, const int* in_sizes, int n_in,
                              void* d_out, int out_size, void* d_ws, size_t ws_size,
                              hipStream_t stream) {
    const int*   idx  = (const int*)  d_in[0];
    const float* emb  = (const float*)d_in[1];
    const float* A    = (const float*)d_in[2];
    const float* Bm   = (const float*)d_in[3];
    const float* bias = (const float*)d_in[4];
    float* out = (float*)d_out;

    const int ntok = in_sizes[0];                       // 8*4096 = 32768
    const int blocks = (ntok + TOKS_PER_BLOCK - 1) / TOKS_PER_BLOCK;

    hipLaunchKernelGGL(lora_embedding_kernel, dim3(blocks), dim3(TPB), 0, stream,
                       idx, emb, A, Bm, bias, out, ntok);
}